// Round 4
// baseline (798.622 us; speedup 1.0000x reference)
//
#include <hip/hip_runtime.h>
#include <hip/hip_bf16.h>

#define N_NODES   50000
#define N_PAD     50048                 // ceil64
#define N_EDGES   800000
#define N_REL     16
#define N_GRAPHS  64
#define DIM       128
#define FC_DIM    256
#define N_CLASSES 16

#define NBINS     (N_PAD * 16)          // 800768, dst-major: key = dst*16 + rel
#define NBLK_SCAN 782
#define NTILES    782                   // N_PAD / 64
#define POOL_CH   64

// ---- ws layout (bytes, 256-aligned) ----
#define WS_HIST   0                     // 3203072 (NBINS*4)  } one contiguous
#define WS_HG     3203072               // 32768              } memset region
#define WS_CNT    3235840               // 256                }
#define MEMSET_SZ 3236096
#define WS_OFFS   3236096               // (NBINS+1)*4
#define WS_CUR    6439424               // NBINS*4
#define WS_PART   9642496               // 4096
#define WS_SRCS   9646592               // 3200000
#define WS_X1     12846592              // 50048*128*2 = 12812288
#define WS_X2     25658880              // 12812288
#define WS_AGG2   38471168              // 50048*128*4 = 25624576
#define WS_WB     64095744              // 2 * 17*128*128*2 = 1114112

typedef __attribute__((ext_vector_type(8))) short bf16x8;
typedef __attribute__((ext_vector_type(4))) float f32x4;

__device__ __forceinline__ void atomAddF(float* p, float v) {
#if defined(__gfx90a__) || defined(__gfx942__) || defined(__gfx950__)
    unsafeAtomicAdd(p, v);
#else
    atomicAdd(p, v);
#endif
}

__device__ __forceinline__ float bf2f(unsigned int u) {
    union { float f; unsigned int i; } x; x.i = u << 16; return x.f;
}
__device__ __forceinline__ unsigned short f2bf(float f) {
    union { float f; unsigned int u; } x; x.f = f;
    unsigned int r = x.u + 0x7fff + ((x.u >> 16) & 1);
    return (unsigned short)(r >> 16);
}

__device__ __forceinline__ void accum8(float* qa, uint4 u) {
    qa[0] += bf2f(u.x & 0xffff); qa[1] += bf2f(u.x >> 16);
    qa[2] += bf2f(u.y & 0xffff); qa[3] += bf2f(u.y >> 16);
    qa[4] += bf2f(u.z & 0xffff); qa[5] += bf2f(u.z >> 16);
    qa[6] += bf2f(u.w & 0xffff); qa[7] += bf2f(u.w >> 16);
}
__device__ __forceinline__ void pack32(const float* qa, unsigned short* dst) {
    #pragma unroll
    for (int j = 0; j < 4; ++j) {
        uint4 w;
        w.x = ((unsigned int)f2bf(qa[j*8+1]) << 16) | f2bf(qa[j*8+0]);
        w.y = ((unsigned int)f2bf(qa[j*8+3]) << 16) | f2bf(qa[j*8+2]);
        w.z = ((unsigned int)f2bf(qa[j*8+5]) << 16) | f2bf(qa[j*8+4]);
        w.w = ((unsigned int)f2bf(qa[j*8+7]) << 16) | f2bf(qa[j*8+6]);
        ((uint4*)dst)[j] = w;
    }
}

// bounds for rel r of this lane-group's dst; ov holds rels s*4..s*4+3
__device__ __forceinline__ int getb(int4 ov, int r, int grp) {
    int c = r & 3;
    int v = (c == 0) ? ov.x : (c == 1) ? ov.y : (c == 2) ? ov.z : ov.w;
    return __shfl(v, grp + (r >> 2), 64);
}

// ---- x1 = bf16(h), zero-padded rows ----
__global__ void k_convX(const float* __restrict__ h, unsigned short* __restrict__ x1) {
    int i = blockIdx.x * blockDim.x + threadIdx.x;      // over N_PAD*DIM
    int v = i >> 7;
    x1[i] = (v < N_NODES) ? f2bf(h[i]) : (unsigned short)0;
}

// ---- Wb[l][r][n][k] = bf16(W_l[r][k][n]); r==16 -> Ws_l ---- (both layers)
__global__ void k_convW(const float* __restrict__ W1, const float* __restrict__ Ws1,
                        const float* __restrict__ W2, const float* __restrict__ Ws2,
                        unsigned short* __restrict__ Wb) {
    int id = blockIdx.x * blockDim.x + threadIdx.x;     // 2*17*16384
    int l = id / 278528, rem = id % 278528;
    int r = rem >> 14, rr = rem & 16383;
    int n = rr >> 7, k = rr & 127;
    const float* W  = l ? W2 : W1;
    const float* Ws = l ? Ws2 : Ws1;
    float v = (r < 16) ? W[r * 16384 + k * 128 + n] : Ws[k * 128 + n];
    Wb[id] = f2bf(v);
}

__global__ void k_histK(const int* __restrict__ dst, const int* __restrict__ rel,
                        int* __restrict__ hist) {
    int e = blockIdx.x * blockDim.x + threadIdx.x;
    if (e < N_EDGES) atomicAdd(&hist[dst[e] * 16 + rel[e]], 1);
}

__global__ void k_scanA(const int* __restrict__ hist, int* __restrict__ partials) {
    __shared__ int red[256];
    int b = blockIdx.x, t = threadIdx.x;
    int4 v = ((const int4*)(hist + b * 1024))[t];
    red[t] = v.x + v.y + v.z + v.w;
    __syncthreads();
    for (int o = 128; o > 0; o >>= 1) {
        if (t < o) red[t] += red[t + o];
        __syncthreads();
    }
    if (t == 0) partials[b] = red[0];
}

__global__ void k_scanB(int* __restrict__ partials, int* __restrict__ offs_tail) {
    __shared__ int s1[256], s2[256];
    int t = threadIdx.x;
    int v[4]; int sum = 0;
    #pragma unroll
    for (int i = 0; i < 4; ++i) {
        int j = t * 4 + i;
        v[i] = (j < NBLK_SCAN) ? partials[j] : 0;
        sum += v[i];
    }
    s1[t] = sum; __syncthreads();
    int* cur = s1; int* nxt = s2;
    for (int o = 1; o < 256; o <<= 1) {
        nxt[t] = cur[t] + ((t >= o) ? cur[t - o] : 0);
        __syncthreads();
        int* tmp = cur; cur = nxt; nxt = tmp;
    }
    int run = cur[t] - sum;
    #pragma unroll
    for (int i = 0; i < 4; ++i) {
        int j = t * 4 + i;
        if (j < NBLK_SCAN) partials[j] = run;
        run += v[i];
    }
    if (t == 255) offs_tail[0] = cur[255];
}

__global__ void k_scanC(const int* __restrict__ hist, const int* __restrict__ partials,
                        int* __restrict__ offs, int* __restrict__ curp) {
    __shared__ int s1[256], s2[256];
    int b = blockIdx.x, t = threadIdx.x;
    int4 v = ((const int4*)(hist + b * 1024))[t];
    int sum = v.x + v.y + v.z + v.w;
    s1[t] = sum; __syncthreads();
    int* cur = s1; int* nxt = s2;
    for (int o = 1; o < 256; o <<= 1) {
        nxt[t] = cur[t] + ((t >= o) ? cur[t - o] : 0);
        __syncthreads();
        int* tmp = cur; cur = nxt; nxt = tmp;
    }
    int base = partials[b] + cur[t] - sum;
    int4 w;
    w.x = base;
    w.y = base + v.x;
    w.z = w.y + v.y;
    w.w = w.z + v.z;
    ((int4*)(offs + b * 1024))[t] = w;
    ((int4*)(curp + b * 1024))[t] = w;
}

__global__ void k_scatterK(const int* __restrict__ src, const int* __restrict__ dst,
                           const int* __restrict__ rel, int* __restrict__ cur,
                           int* __restrict__ srcs) {
    int e = blockIdx.x * blockDim.x + threadIdx.x;
    if (e < N_EDGES) {
        int key = dst[e] * 16 + rel[e];
        int pos = atomicAdd(&cur[key], 1);
        srcs[pos] = src[e];
    }
}

// ---- fused RGCN layer, BARRIER-FREE ----
// Block: 64 dsts, 4 waves. Wave w owns dsts [w*16, w*16+16) x ALL 128 cols.
// Its Q-quarter is built by its own lanes -> LDS deps are intra-wave, no __syncthreads.
#define QT_STRIDE 136
__global__ __launch_bounds__(256, 3) void k_layer(
    const unsigned short* __restrict__ x, const unsigned short* __restrict__ Wb,
    const int* __restrict__ offs, const int* __restrict__ srcs,
    const float* __restrict__ bias,
    unsigned short* __restrict__ out_bf16, float* __restrict__ out_f32)
{
    __shared__ unsigned short Qt[64 * QT_STRIDE];        // 17408 B

    int tid = threadIdx.x;
    int w = tid >> 6, l = tid & 63;
    int v0 = blockIdx.x * 64;
    int g = l >> 2, s = l & 3;                           // build: 4 lanes/dst, 32 feats
    int dst = v0 + w * 16 + g;
    int nl = l & 15, q = l >> 4;                         // mfma roles
    int grp = l & ~3;

    unsigned short* qrow = Qt + (w * 16 + g) * QT_STRIDE + s * 32;

    // preload all 17 bounds for this dst: ov = rels s*4..s*4+3, evv = end of rel 15
    const int4 ov = *((const int4*)(offs + dst * 16) + s);
    const int evv = offs[dst * 16 + 16];

    f32x4 acc[8];
    #pragma unroll
    for (int i = 0; i < 8; ++i) acc[i] = (f32x4){0.f, 0.f, 0.f, 0.f};

    for (int r = 0; r < 17; ++r) {
        int beg, end;
        if (r < 16) {
            beg = getb(ov, r, grp);
            end = (r < 15) ? getb(ov, r + 1, grp) : evv;
        } else { beg = 0; end = 1; }
        int deg = end - beg;

        if (deg <= 0) {
            uint4 z = {0u, 0u, 0u, 0u};
            uint4* qp = (uint4*)qrow;
            qp[0] = z; qp[1] = z; qp[2] = z; qp[3] = z;
        } else {
            int s0 = (r == 16) ? dst : srcs[beg];
            const uint4* xr = (const uint4*)(x + s0 * 128 + s * 32);
            uint4 p0 = xr[0], p1 = xr[1], p2 = xr[2], p3 = xr[3];
            if (deg == 1) {
                uint4* qp = (uint4*)qrow;                // bf16 passthrough (74% of bins)
                qp[0] = p0; qp[1] = p1; qp[2] = p2; qp[3] = p3;
            } else {
                float qa[32];
                #pragma unroll
                for (int i = 0; i < 32; ++i) qa[i] = 0.f;
                accum8(qa +  0, p0); accum8(qa +  8, p1);
                accum8(qa + 16, p2); accum8(qa + 24, p3);
                for (int e = beg + 1; e < end; ++e) {
                    const uint4* x2 = (const uint4*)(x + srcs[e] * 128 + s * 32);
                    uint4 u0 = x2[0], u1 = x2[1], u2 = x2[2], u3 = x2[3];
                    accum8(qa +  0, u0); accum8(qa +  8, u1);
                    accum8(qa + 16, u2); accum8(qa + 24, u3);
                }
                pack32(qa, qrow);
            }
        }

        // ---- MFMA: wave's 16 rows x 128 cols (intra-wave lgkm dep only) ----
        const unsigned short* qbase = Qt + (w * 16 + nl) * QT_STRIDE + q * 8;
        bf16x8 a0 = *(const bf16x8*)(qbase +  0);
        bf16x8 a1 = *(const bf16x8*)(qbase + 32);
        bf16x8 a2 = *(const bf16x8*)(qbase + 64);
        bf16x8 a3 = *(const bf16x8*)(qbase + 96);
        const unsigned short* wr = Wb + r * 16384 + nl * 128 + q * 8;
        #pragma unroll
        for (int nt = 0; nt < 8; ++nt) {
            const unsigned short* wp = wr + nt * 16 * 128;
            bf16x8 b0 = *(const bf16x8*)(wp +  0);
            bf16x8 b1 = *(const bf16x8*)(wp + 32);
            bf16x8 b2 = *(const bf16x8*)(wp + 64);
            bf16x8 b3 = *(const bf16x8*)(wp + 96);
            acc[nt] = __builtin_amdgcn_mfma_f32_16x16x32_bf16(a0, b0, acc[nt], 0, 0, 0);
            acc[nt] = __builtin_amdgcn_mfma_f32_16x16x32_bf16(a1, b1, acc[nt], 0, 0, 0);
            acc[nt] = __builtin_amdgcn_mfma_f32_16x16x32_bf16(a2, b2, acc[nt], 0, 0, 0);
            acc[nt] = __builtin_amdgcn_mfma_f32_16x16x32_bf16(a3, b3, acc[nt], 0, 0, 0);
        }
    }

    // ---- epilogue: C layout col=lane&15, row=q*4+reg ----
    #pragma unroll
    for (int nt = 0; nt < 8; ++nt) {
        int col = nt * 16 + nl;
        float bv = bias[col];
        #pragma unroll
        for (int reg = 0; reg < 4; ++reg) {
            int node = v0 + w * 16 + q * 4 + reg;
            float val = acc[nt][reg] + bv;
            if (out_bf16) out_bf16[node * 128 + col] = f2bf(fmaxf(val, 0.f));
            else          out_f32[node * 128 + col]  = val;
        }
    }
}

__global__ void k_pool(const float* __restrict__ agg2, const int* __restrict__ gids,
                       float* __restrict__ hg_sum, int* __restrict__ cnt)
{
    int d  = threadIdx.x;                    // 128
    int n0 = blockIdx.x * POOL_CH;
    int nend = min(n0 + POOL_CH, N_NODES);
    int curg = gids[n0];
    float run = 0.f;
    for (int n = n0; n < nend; ++n) {
        int g = gids[n];
        if (g != curg) { atomAddF(&hg_sum[curg*DIM + d], run); run = 0.f; curg = g; }
        run += fmaxf(agg2[n*DIM + d], 0.f);
    }
    atomAddF(&hg_sum[curg*DIM + d], run);
    if (d == 0) {
        int cg = gids[n0]; int rl = 0;
        for (int n = n0; n < nend; ++n) {
            int g = gids[n];
            if (g != cg) { atomicAdd(&cnt[cg], rl); rl = 0; cg = g; }
            rl++;
        }
        atomicAdd(&cnt[cg], rl);
    }
}

__global__ __launch_bounds__(256) void k_head(
    const float* __restrict__ hg_sum, const int* __restrict__ cnt,
    const float* __restrict__ Wfc, const float* __restrict__ bfc,
    const float* __restrict__ Wc, const float* __restrict__ bc,
    float* __restrict__ out)
{
    int g = blockIdx.x, t = threadIdx.x;
    __shared__ float hgl[DIM];
    __shared__ float fcl[FC_DIM];
    __shared__ float lg[N_CLASSES];
    if (t < DIM) {
        float c = (float)max(cnt[g], 1);
        hgl[t] = hg_sum[g*DIM + t] / c;
    }
    __syncthreads();
    {
        float sv = bfc[t];
        #pragma unroll 4
        for (int k = 0; k < DIM; ++k) sv += hgl[k] * Wfc[k*FC_DIM + t];
        fcl[t] = fmaxf(sv, 0.f);
    }
    __syncthreads();
    if (t < N_CLASSES) {
        float lgt = bc[t];
        #pragma unroll 4
        for (int k = 0; k < FC_DIM; ++k) lgt += fcl[k] * Wc[k*N_CLASSES + t];
        lg[t] = lgt;
    }
    __syncthreads();
    if (t < N_CLASSES) {
        float m = lg[0];
        #pragma unroll
        for (int c = 1; c < N_CLASSES; ++c) m = fmaxf(m, lg[c]);
        float sden = 0.f;
        #pragma unroll
        for (int c = 0; c < N_CLASSES; ++c) sden += expf(lg[c] - m);
        out[g*N_CLASSES + t] = expf(lg[t] - m) / sden;
    }
}

extern "C" void kernel_launch(void* const* d_in, const int* in_sizes, int n_in,
                              void* d_out, int out_size, void* d_ws, size_t ws_size,
                              hipStream_t stream)
{
    const float* h   = (const float*)d_in[0];
    const int*   src = (const int*)d_in[1];
    const int*   dst = (const int*)d_in[2];
    const int*   rel = (const int*)d_in[3];
    const int*   gid = (const int*)d_in[4];
    const float* W1  = (const float*)d_in[5];
    const float* Ws1 = (const float*)d_in[6];
    const float* b1  = (const float*)d_in[7];
    const float* W2  = (const float*)d_in[8];
    const float* Ws2 = (const float*)d_in[9];
    const float* b2  = (const float*)d_in[10];
    const float* Wfc = (const float*)d_in[11];
    const float* bfc = (const float*)d_in[12];
    const float* Wc  = (const float*)d_in[13];
    const float* bc  = (const float*)d_in[14];
    float* out = (float*)d_out;

    char* ws = (char*)d_ws;
    int*   hist  = (int*)(ws + WS_HIST);
    float* hgsum = (float*)(ws + WS_HG);
    int*   cnt   = (int*)(ws + WS_CNT);
    int*   offs  = (int*)(ws + WS_OFFS);
    int*   cur   = (int*)(ws + WS_CUR);
    int*   part  = (int*)(ws + WS_PART);
    int*   srcs  = (int*)(ws + WS_SRCS);
    unsigned short* x1  = (unsigned short*)(ws + WS_X1);
    unsigned short* x2  = (unsigned short*)(ws + WS_X2);
    float* agg2  = (float*)(ws + WS_AGG2);
    unsigned short* Wb1 = (unsigned short*)(ws + WS_WB);
    unsigned short* Wb2 = Wb1 + 17 * 16384;

    hipMemsetAsync(hist, 0, MEMSET_SZ, stream);   // hist + hgsum + cnt contiguous

    k_convX<<<(N_PAD * DIM) / 256, 256, 0, stream>>>(h, x1);
    k_convW<<<(2 * 17 * 16384) / 256, 256, 0, stream>>>(W1, Ws1, W2, Ws2, Wb1);

    k_histK<<<(N_EDGES + 255) / 256, 256, 0, stream>>>(dst, rel, hist);
    k_scanA<<<NBLK_SCAN, 256, 0, stream>>>(hist, part);
    k_scanB<<<1, 256, 0, stream>>>(part, offs + NBINS);
    k_scanC<<<NBLK_SCAN, 256, 0, stream>>>(hist, part, offs, cur);
    k_scatterK<<<(N_EDGES + 255) / 256, 256, 0, stream>>>(src, dst, rel, cur, srcs);

    k_layer<<<NTILES, 256, 0, stream>>>(x1, Wb1, offs, srcs, b1, x2, nullptr);
    k_layer<<<NTILES, 256, 0, stream>>>(x2, Wb2, offs, srcs, b2, nullptr, agg2);

    k_pool<<<(N_NODES + POOL_CH - 1) / POOL_CH, 128, 0, stream>>>(agg2, gid, hgsum, cnt);
    k_head<<<N_GRAPHS, 256, 0, stream>>>(hgsum, cnt, Wfc, bfc, Wc, bc, out);
}

// Round 5
// 734.039 us; speedup vs baseline: 1.0880x; 1.0880x over previous
//
#include <hip/hip_runtime.h>
#include <hip/hip_bf16.h>

#define N_NODES   50000
#define N_PAD     50048                 // ceil64
#define N_EDGES   800000
#define N_REL     16
#define N_GRAPHS  64
#define DIM       128
#define FC_DIM    256
#define N_CLASSES 16

#define NBINS     (N_REL * N_PAD)       // 800768, rel-major: key = rel*N_PAD + dst
#define NBLK_SCAN 782
#define NTILES    782                   // N_PAD / 64
#define POOL_CH   64

// ---- ws layout (bytes, 256-aligned) ----
#define WS_HIST   0                     // 3203072 (NBINS*4)  } one contiguous
#define WS_HG     3203072               // 32768              } memset region
#define WS_CNT    3235840               // 256                }
#define MEMSET_SZ 3236096
#define WS_OFFS   3236096               // (NBINS+1)*4
#define WS_CUR    6439424               // NBINS*4
#define WS_PART   9642496               // 4096
#define WS_SRCS   9646592               // 3200000
#define WS_X1     12846592              // 50048*128*2 = 12812288
#define WS_X2     25658880              // 12812288
#define WS_AGG2   38471168              // 50048*128*4 = 25624576
#define WS_WB     64095744              // 2 * 17*128*128*2 = 1114112

typedef __attribute__((ext_vector_type(8))) short bf16x8;
typedef __attribute__((ext_vector_type(4))) float f32x4;

__device__ __forceinline__ void atomAddF(float* p, float v) {
#if defined(__gfx90a__) || defined(__gfx942__) || defined(__gfx950__)
    unsafeAtomicAdd(p, v);
#else
    atomicAdd(p, v);
#endif
}

__device__ __forceinline__ float bf2f(unsigned int u) {
    union { float f; unsigned int i; } x; x.i = u << 16; return x.f;
}
__device__ __forceinline__ unsigned short f2bf(float f) {
    union { float f; unsigned int u; } x; x.f = f;
    unsigned int r = x.u + 0x7fff + ((x.u >> 16) & 1);
    return (unsigned short)(r >> 16);
}

__device__ __forceinline__ void accum8(float* qa, uint4 u) {
    qa[0] += bf2f(u.x & 0xffff); qa[1] += bf2f(u.x >> 16);
    qa[2] += bf2f(u.y & 0xffff); qa[3] += bf2f(u.y >> 16);
    qa[4] += bf2f(u.z & 0xffff); qa[5] += bf2f(u.z >> 16);
    qa[6] += bf2f(u.w & 0xffff); qa[7] += bf2f(u.w >> 16);
}
__device__ __forceinline__ void pack32(const float* qa, unsigned short* dst) {
    #pragma unroll
    for (int j = 0; j < 4; ++j) {
        uint4 w;
        w.x = ((unsigned int)f2bf(qa[j*8+1]) << 16) | f2bf(qa[j*8+0]);
        w.y = ((unsigned int)f2bf(qa[j*8+3]) << 16) | f2bf(qa[j*8+2]);
        w.z = ((unsigned int)f2bf(qa[j*8+5]) << 16) | f2bf(qa[j*8+4]);
        w.w = ((unsigned int)f2bf(qa[j*8+7]) << 16) | f2bf(qa[j*8+6]);
        ((uint4*)dst)[j] = w;
    }
}

// ---- x1 = bf16(h), zero-padded rows ----
__global__ void k_convX(const float* __restrict__ h, unsigned short* __restrict__ x1) {
    int i = blockIdx.x * blockDim.x + threadIdx.x;      // over N_PAD*DIM
    int v = i >> 7;
    x1[i] = (v < N_NODES) ? f2bf(h[i]) : (unsigned short)0;
}

// ---- Wb[l][r][n][k] = bf16(W_l[r][k][n]); r==16 -> Ws_l ---- (both layers)
__global__ void k_convW(const float* __restrict__ W1, const float* __restrict__ Ws1,
                        const float* __restrict__ W2, const float* __restrict__ Ws2,
                        unsigned short* __restrict__ Wb) {
    int id = blockIdx.x * blockDim.x + threadIdx.x;     // 2*17*16384
    int l = id / 278528, rem = id % 278528;
    int r = rem >> 14, rr = rem & 16383;
    int n = rr >> 7, k = rr & 127;
    const float* W  = l ? W2 : W1;
    const float* Ws = l ? Ws2 : Ws1;
    float v = (r < 16) ? W[r * 16384 + k * 128 + n] : Ws[k * 128 + n];
    Wb[id] = f2bf(v);
}

__global__ void k_histK(const int* __restrict__ dst, const int* __restrict__ rel,
                        int* __restrict__ hist) {
    int e = blockIdx.x * blockDim.x + threadIdx.x;
    if (e < N_EDGES) atomicAdd(&hist[rel[e] * N_PAD + dst[e]], 1);
}

__global__ void k_scanA(const int* __restrict__ hist, int* __restrict__ partials) {
    __shared__ int red[256];
    int b = blockIdx.x, t = threadIdx.x;
    int4 v = ((const int4*)(hist + b * 1024))[t];
    red[t] = v.x + v.y + v.z + v.w;
    __syncthreads();
    for (int o = 128; o > 0; o >>= 1) {
        if (t < o) red[t] += red[t + o];
        __syncthreads();
    }
    if (t == 0) partials[b] = red[0];
}

__global__ void k_scanB(int* __restrict__ partials, int* __restrict__ offs_tail) {
    __shared__ int s1[256], s2[256];
    int t = threadIdx.x;
    int v[4]; int sum = 0;
    #pragma unroll
    for (int i = 0; i < 4; ++i) {
        int j = t * 4 + i;
        v[i] = (j < NBLK_SCAN) ? partials[j] : 0;
        sum += v[i];
    }
    s1[t] = sum; __syncthreads();
    int* cur = s1; int* nxt = s2;
    for (int o = 1; o < 256; o <<= 1) {
        nxt[t] = cur[t] + ((t >= o) ? cur[t - o] : 0);
        __syncthreads();
        int* tmp = cur; cur = nxt; nxt = tmp;
    }
    int run = cur[t] - sum;
    #pragma unroll
    for (int i = 0; i < 4; ++i) {
        int j = t * 4 + i;
        if (j < NBLK_SCAN) partials[j] = run;
        run += v[i];
    }
    if (t == 255) offs_tail[0] = cur[255];
}

__global__ void k_scanC(const int* __restrict__ hist, const int* __restrict__ partials,
                        int* __restrict__ offs, int* __restrict__ curp) {
    __shared__ int s1[256], s2[256];
    int b = blockIdx.x, t = threadIdx.x;
    int4 v = ((const int4*)(hist + b * 1024))[t];
    int sum = v.x + v.y + v.z + v.w;
    s1[t] = sum; __syncthreads();
    int* cur = s1; int* nxt = s2;
    for (int o = 1; o < 256; o <<= 1) {
        nxt[t] = cur[t] + ((t >= o) ? cur[t - o] : 0);
        __syncthreads();
        int* tmp = cur; cur = nxt; nxt = tmp;
    }
    int base = partials[b] + cur[t] - sum;
    int4 w;
    w.x = base;
    w.y = base + v.x;
    w.z = w.y + v.y;
    w.w = w.z + v.z;
    ((int4*)(offs + b * 1024))[t] = w;
    ((int4*)(curp + b * 1024))[t] = w;
}

__global__ void k_scatterK(const int* __restrict__ src, const int* __restrict__ dst,
                           const int* __restrict__ rel, int* __restrict__ cur,
                           int* __restrict__ srcs) {
    int e = blockIdx.x * blockDim.x + threadIdx.x;
    if (e < N_EDGES) {
        int key = rel[e] * N_PAD + dst[e];
        int pos = atomicAdd(&cur[key], 1);
        srcs[pos] = src[e];
    }
}

// ---- fused RGCN layer: bulk-staged gathers + MFMA ----
// Block = 64 dsts. Per rel: all 256 threads bulk-load up to 96 edge rows into
// registers (6x16B chunks each, fully independent -> deep MLP), ds_write into
// a single LDS stage buffer AFTER the current rel's MFMA (regs bridge reuse).
// Segment-sum reads LDS only. B col-split in regs (wave w: cols [w*32,w*32+32)).
#define CAP   96
#define SSTR  136   // stage/Q row stride in bf16 elems (272 B)
__global__ __launch_bounds__(256, 2) void k_layer(
    const unsigned short* __restrict__ x, const unsigned short* __restrict__ Wb,
    const int* __restrict__ offs, const int* __restrict__ srcs,
    const float* __restrict__ bias,
    unsigned short* __restrict__ out_bf16, float* __restrict__ out_f32)
{
    __shared__ unsigned short sbuf[CAP * SSTR];   // 26112 B
    __shared__ unsigned short Qt[64 * SSTR];      // 17408 B
    __shared__ int sBnd[17 * 65];                 // 4420 B: begs[r][d], d=0..64

    int tid = threadIdx.x;
    int w = tid >> 6, l = tid & 63;
    int v0 = blockIdx.x * 64;
    int g = tid >> 2, s = tid & 3;               // segsum: 4 lanes/dst, 32 feats
    int nl = l & 15, q = l >> 4;                 // mfma roles
    int chunk = l & 15;                          // staging chunk (16 B)
    int erow = l >> 4;                           // staging edge-within-issue

    // ---- preload all bounds: sBnd[r*65+d] = offs[r*N_PAD + v0 + d] ----
    for (int i = tid; i < 17 * 65; i += 256) {
        int rr = i / 65, d = i - rr * 65;
        sBnd[i] = offs[rr * N_PAD + v0 + d];
    }
    __syncthreads();

    // ---- preloop: stage rel 0 ----
    {
        int begB = sBnd[0], S = sBnd[64] - begB;
        int Sc = (S > 0) ? S - 1 : 0;
        #pragma unroll
        for (int i = 0; i < 6; ++i) {
            int eloc = (w + i * 4) * 4 + erow;
            int sv = (S > 0) ? srcs[begB + min(eloc, Sc)] : 0;
            uint4 vv = *(const uint4*)(x + sv * 128 + chunk * 8);
            *(uint4*)(&sbuf[eloc * SSTR + chunk * 8]) = vv;
        }
    }
    __syncthreads();

    f32x4 acc[4][2];
    #pragma unroll
    for (int m = 0; m < 4; ++m) {
        acc[m][0] = (f32x4){0.f, 0.f, 0.f, 0.f};
        acc[m][1] = (f32x4){0.f, 0.f, 0.f, 0.f};
    }
    uint4 selfR[4];

    for (int r = 0; r < 17; ++r) {
        // ---- issue stage loads for rel r+1 (held in regs until after MFMA) ----
        uint4 st[6];
        int rn = r + 1;
        bool doStage = (rn < 16);
        if (doStage) {
            int begB = sBnd[rn * 65], S = sBnd[rn * 65 + 64] - begB;
            int Sc = (S > 0) ? S - 1 : 0;
            #pragma unroll
            for (int i = 0; i < 6; ++i) {
                int eloc = (w + i * 4) * 4 + erow;
                int sv = (S > 0) ? srcs[begB + min(eloc, Sc)] : 0;
                st[i] = *(const uint4*)(x + sv * 128 + chunk * 8);
            }
        }
        if (r == 15) {                           // prefetch own row for self-loop
            #pragma unroll
            for (int c = 0; c < 4; ++c)
                selfR[c] = *(const uint4*)(x + (v0 + g) * 128 + s * 32 + c * 8);
        }
        // ---- B fragments for rel r (global, L2-resident) ----
        bf16x8 Bf[2][4];
        {
            const unsigned short* wr = Wb + r * 16384;
            #pragma unroll
            for (int nt = 0; nt < 2; ++nt) {
                int n = w * 32 + nt * 16 + nl;
                #pragma unroll
                for (int kc = 0; kc < 4; ++kc)
                    Bf[nt][kc] = *(const bf16x8*)(wr + n * 128 + kc * 32 + q * 8);
            }
        }
        // ---- segment-sum rel r from LDS stage -> Qt ----
        unsigned short* qrow = Qt + g * SSTR + s * 32;
        if (r == 16) {
            uint4* qp = (uint4*)qrow;
            qp[0] = selfR[0]; qp[1] = selfR[1]; qp[2] = selfR[2]; qp[3] = selfR[3];
        } else {
            int beg = sBnd[r * 65 + g], end = sBnd[r * 65 + g + 1];
            int begB = sBnd[r * 65];
            int cnt = end - beg;
            uint4* qp = (uint4*)qrow;
            if (cnt == 0) {
                uint4 z = {0u, 0u, 0u, 0u};
                qp[0] = z; qp[1] = z; qp[2] = z; qp[3] = z;
            } else if (cnt == 1) {
                int slot = beg - begB;
                if (slot < CAP) {
                    const uint4* sp = (const uint4*)&sbuf[slot * SSTR + s * 32];
                    qp[0] = sp[0]; qp[1] = sp[1]; qp[2] = sp[2]; qp[3] = sp[3];
                } else {
                    int sv = srcs[beg];
                    const uint4* xp = (const uint4*)(x + sv * 128 + s * 32);
                    qp[0] = xp[0]; qp[1] = xp[1]; qp[2] = xp[2]; qp[3] = xp[3];
                }
            } else {
                float qa[32];
                #pragma unroll
                for (int i = 0; i < 32; ++i) qa[i] = 0.f;
                for (int e = beg; e < end; ++e) {
                    int slot = e - begB;
                    if (slot < CAP) {
                        const uint4* sp = (const uint4*)&sbuf[slot * SSTR + s * 32];
                        uint4 u0 = sp[0], u1 = sp[1], u2 = sp[2], u3 = sp[3];
                        accum8(qa + 0, u0); accum8(qa + 8, u1);
                        accum8(qa + 16, u2); accum8(qa + 24, u3);
                    } else {                     // rare overflow fallback
                        int sv = srcs[e];
                        const uint4* xp = (const uint4*)(x + sv * 128 + s * 32);
                        uint4 u0 = xp[0], u1 = xp[1], u2 = xp[2], u3 = xp[3];
                        accum8(qa + 0, u0); accum8(qa + 8, u1);
                        accum8(qa + 16, u2); accum8(qa + 24, u3);
                    }
                }
                pack32(qa, qrow);
            }
        }
        __syncthreads();                         // barrier1: Qt ready, sbuf free

        // ---- MFMA rel r: 64 rows x wave's 32 cols ----
        #pragma unroll
        for (int kc = 0; kc < 4; ++kc) {
            bf16x8 a[4];
            #pragma unroll
            for (int m = 0; m < 4; ++m)
                a[m] = *(const bf16x8*)(&Qt[(m * 16 + nl) * SSTR + kc * 32 + q * 8]);
            #pragma unroll
            for (int m = 0; m < 4; ++m) {
                acc[m][0] = __builtin_amdgcn_mfma_f32_16x16x32_bf16(a[m], Bf[0][kc], acc[m][0], 0, 0, 0);
                acc[m][1] = __builtin_amdgcn_mfma_f32_16x16x32_bf16(a[m], Bf[1][kc], acc[m][1], 0, 0, 0);
            }
        }

        // ---- write staged regs for rel r+1 into sbuf ----
        if (doStage) {
            #pragma unroll
            for (int i = 0; i < 6; ++i) {
                int eloc = (w + i * 4) * 4 + erow;
                *(uint4*)(&sbuf[eloc * SSTR + chunk * 8]) = st[i];
            }
        }
        __syncthreads();                         // barrier2: sbuf ready
    }

    // ---- epilogue: C layout col=lane&15, row=q*4+reg ----
    #pragma unroll
    for (int m = 0; m < 4; ++m) {
        #pragma unroll
        for (int nt = 0; nt < 2; ++nt) {
            int col = w * 32 + nt * 16 + nl;
            float bv = bias[col];
            #pragma unroll
            for (int reg = 0; reg < 4; ++reg) {
                int node = v0 + m * 16 + q * 4 + reg;
                float val = acc[m][nt][reg] + bv;
                if (out_bf16) out_bf16[node * 128 + col] = f2bf(fmaxf(val, 0.f));
                else          out_f32[node * 128 + col]  = val;
            }
        }
    }
}

__global__ void k_pool(const float* __restrict__ agg2, const int* __restrict__ gids,
                       float* __restrict__ hg_sum, int* __restrict__ cnt)
{
    int d  = threadIdx.x;                    // 128
    int n0 = blockIdx.x * POOL_CH;
    int nend = min(n0 + POOL_CH, N_NODES);
    int curg = gids[n0];
    float run = 0.f;
    for (int n = n0; n < nend; ++n) {
        int g = gids[n];
        if (g != curg) { atomAddF(&hg_sum[curg*DIM + d], run); run = 0.f; curg = g; }
        run += fmaxf(agg2[n*DIM + d], 0.f);
    }
    atomAddF(&hg_sum[curg*DIM + d], run);
    if (d == 0) {
        int cg = gids[n0]; int rl = 0;
        for (int n = n0; n < nend; ++n) {
            int g = gids[n];
            if (g != cg) { atomicAdd(&cnt[cg], rl); rl = 0; cg = g; }
            rl++;
        }
        atomicAdd(&cnt[cg], rl);
    }
}

__global__ __launch_bounds__(256) void k_head(
    const float* __restrict__ hg_sum, const int* __restrict__ cnt,
    const float* __restrict__ Wfc, const float* __restrict__ bfc,
    const float* __restrict__ Wc, const float* __restrict__ bc,
    float* __restrict__ out)
{
    int g = blockIdx.x, t = threadIdx.x;
    __shared__ float hgl[DIM];
    __shared__ float fcl[FC_DIM];
    __shared__ float lg[N_CLASSES];
    if (t < DIM) {
        float c = (float)max(cnt[g], 1);
        hgl[t] = hg_sum[g*DIM + t] / c;
    }
    __syncthreads();
    {
        float sv = bfc[t];
        #pragma unroll 4
        for (int k = 0; k < DIM; ++k) sv += hgl[k] * Wfc[k*FC_DIM + t];
        fcl[t] = fmaxf(sv, 0.f);
    }
    __syncthreads();
    if (t < N_CLASSES) {
        float lgt = bc[t];
        #pragma unroll 4
        for (int k = 0; k < FC_DIM; ++k) lgt += fcl[k] * Wc[k*N_CLASSES + t];
        lg[t] = lgt;
    }
    __syncthreads();
    if (t < N_CLASSES) {
        float m = lg[0];
        #pragma unroll
        for (int c = 1; c < N_CLASSES; ++c) m = fmaxf(m, lg[c]);
        float sden = 0.f;
        #pragma unroll
        for (int c = 0; c < N_CLASSES; ++c) sden += expf(lg[c] - m);
        out[g*N_CLASSES + t] = expf(lg[t] - m) / sden;
    }
}

extern "C" void kernel_launch(void* const* d_in, const int* in_sizes, int n_in,
                              void* d_out, int out_size, void* d_ws, size_t ws_size,
                              hipStream_t stream)
{
    const float* h   = (const float*)d_in[0];
    const int*   src = (const int*)d_in[1];
    const int*   dst = (const int*)d_in[2];
    const int*   rel = (const int*)d_in[3];
    const int*   gid = (const int*)d_in[4];
    const float* W1  = (const float*)d_in[5];
    const float* Ws1 = (const float*)d_in[6];
    const float* b1  = (const float*)d_in[7];
    const float* W2  = (const float*)d_in[8];
    const float* Ws2 = (const float*)d_in[9];
    const float* b2  = (const float*)d_in[10];
    const float* Wfc = (const float*)d_in[11];
    const float* bfc = (const float*)d_in[12];
    const float* Wc  = (const float*)d_in[13];
    const float* bc  = (const float*)d_in[14];
    float* out = (float*)d_out;

    char* ws = (char*)d_ws;
    int*   hist  = (int*)(ws + WS_HIST);
    float* hgsum = (float*)(ws + WS_HG);
    int*   cnt   = (int*)(ws + WS_CNT);
    int*   offs  = (int*)(ws + WS_OFFS);
    int*   cur   = (int*)(ws + WS_CUR);
    int*   part  = (int*)(ws + WS_PART);
    int*   srcs  = (int*)(ws + WS_SRCS);
    unsigned short* x1  = (unsigned short*)(ws + WS_X1);
    unsigned short* x2  = (unsigned short*)(ws + WS_X2);
    float* agg2  = (float*)(ws + WS_AGG2);
    unsigned short* Wb1 = (unsigned short*)(ws + WS_WB);
    unsigned short* Wb2 = Wb1 + 17 * 16384;

    hipMemsetAsync(hist, 0, MEMSET_SZ, stream);   // hist + hgsum + cnt contiguous

    k_convX<<<(N_PAD * DIM) / 256, 256, 0, stream>>>(h, x1);
    k_convW<<<(2 * 17 * 16384) / 256, 256, 0, stream>>>(W1, Ws1, W2, Ws2, Wb1);

    k_histK<<<(N_EDGES + 255) / 256, 256, 0, stream>>>(dst, rel, hist);
    k_scanA<<<NBLK_SCAN, 256, 0, stream>>>(hist, part);
    k_scanB<<<1, 256, 0, stream>>>(part, offs + NBINS);
    k_scanC<<<NBLK_SCAN, 256, 0, stream>>>(hist, part, offs, cur);
    k_scatterK<<<(N_EDGES + 255) / 256, 256, 0, stream>>>(src, dst, rel, cur, srcs);

    k_layer<<<NTILES, 256, 0, stream>>>(x1, Wb1, offs, srcs, b1, x2, nullptr);
    k_layer<<<NTILES, 256, 0, stream>>>(x2, Wb2, offs, srcs, b2, nullptr, agg2);

    k_pool<<<(N_NODES + POOL_CH - 1) / POOL_CH, 128, 0, stream>>>(agg2, gid, hgsum, cnt);
    k_head<<<N_GRAPHS, 256, 0, stream>>>(hgsum, cnt, Wfc, bfc, Wc, bc, out);
}

// Round 6
// 515.891 us; speedup vs baseline: 1.5480x; 1.4229x over previous
//
#include <hip/hip_runtime.h>
#include <hip/hip_bf16.h>

#define N_NODES   50000
#define N_PAD     50048                 // ceil64 (= 391*128)
#define N_EDGES   800000
#define N_REL     16
#define N_GRAPHS  64
#define DIM       128
#define FC_DIM    256
#define N_CLASSES 16

#define NBINS_D   50176                 // dst bins padded to 49*1024
#define NBLK_SCAN 49
#define NT_A      391                   // N_PAD/128
#define NBLK_B    782                   // N_PAD/64
#define POOL_CH   64

// ---- ws layout (bytes) ----
#define WS_HIST   0                     // 50176*4 = 200704 } contiguous
#define WS_HG     200704                // 32768            } memset
#define WS_CNT    233472                // 256              } region
#define MEMSET_SZ 233728
#define WS_OFFS   233728                // 50208*4 = 200832
#define WS_CUR    434560                // 200704
#define WS_PART   635264                // 256
#define WS_SRCS   635520                // 800000*4 = 3200000
#define WS_X1     3835520               // 50048*128*2 = 12812288
#define WS_X2     16647808              // 12812288
#define WS_AGG    29460096              // bf16 agg: 12812288
#define WS_WB     42272384              // 2*17*128*128*2 = 1114112
#define WS_T      43386496              // + slots * SLOT_BYTES
#define SLOT_BYTES 12812288ull          // N_PAD*128*2

typedef __attribute__((ext_vector_type(8))) short bf16x8;
typedef __attribute__((ext_vector_type(4))) float f32x4;

__device__ __forceinline__ void atomAddF(float* p, float v) {
#if defined(__gfx90a__) || defined(__gfx942__) || defined(__gfx950__)
    unsafeAtomicAdd(p, v);
#else
    atomicAdd(p, v);
#endif
}

__device__ __forceinline__ float bf2f(unsigned int u) {
    union { float f; unsigned int i; } x; x.i = u << 16; return x.f;
}
__device__ __forceinline__ unsigned short f2bf(float f) {
    union { float f; unsigned int u; } x; x.f = f;
    unsigned int r = x.u + 0x7fff + ((x.u >> 16) & 1);
    return (unsigned short)(r >> 16);
}
__device__ __forceinline__ void accum8(float* qa, uint4 u) {
    qa[0] += bf2f(u.x & 0xffff); qa[1] += bf2f(u.x >> 16);
    qa[2] += bf2f(u.y & 0xffff); qa[3] += bf2f(u.y >> 16);
    qa[4] += bf2f(u.z & 0xffff); qa[5] += bf2f(u.z >> 16);
    qa[6] += bf2f(u.w & 0xffff); qa[7] += bf2f(u.w >> 16);
}
__device__ __forceinline__ void pack32(const float* qa, unsigned short* dst) {
    #pragma unroll
    for (int j = 0; j < 4; ++j) {
        uint4 w;
        w.x = ((unsigned int)f2bf(qa[j*8+1]) << 16) | f2bf(qa[j*8+0]);
        w.y = ((unsigned int)f2bf(qa[j*8+3]) << 16) | f2bf(qa[j*8+2]);
        w.z = ((unsigned int)f2bf(qa[j*8+5]) << 16) | f2bf(qa[j*8+4]);
        w.w = ((unsigned int)f2bf(qa[j*8+7]) << 16) | f2bf(qa[j*8+6]);
        ((uint4*)dst)[j] = w;
    }
}

__global__ void k_convX(const float* __restrict__ h, unsigned short* __restrict__ x1) {
    int i = blockIdx.x * blockDim.x + threadIdx.x;      // over N_PAD*DIM
    int v = i >> 7;
    x1[i] = (v < N_NODES) ? f2bf(h[i]) : (unsigned short)0;
}

// Wb[l][r][n][k] = bf16(W_l[r][k][n]); r==16 -> Ws_l
__global__ void k_convW(const float* __restrict__ W1, const float* __restrict__ Ws1,
                        const float* __restrict__ W2, const float* __restrict__ Ws2,
                        unsigned short* __restrict__ Wb) {
    int id = blockIdx.x * blockDim.x + threadIdx.x;     // 2*17*16384
    int l = id / 278528, rem = id % 278528;
    int r = rem >> 14, rr = rem & 16383;
    int n = rr >> 7, k = rr & 127;
    const float* W  = l ? W2 : W1;
    const float* Ws = l ? Ws2 : Ws1;
    float v = (r < 16) ? W[r * 16384 + k * 128 + n] : Ws[k * 128 + n];
    Wb[id] = f2bf(v);
}

__global__ void k_histK(const int* __restrict__ dst, int* __restrict__ hist) {
    int e = blockIdx.x * blockDim.x + threadIdx.x;
    if (e < N_EDGES) atomicAdd(&hist[dst[e]], 1);
}

__global__ void k_scanA(const int* __restrict__ hist, int* __restrict__ partials) {
    __shared__ int red[256];
    int b = blockIdx.x, t = threadIdx.x;
    int4 v = ((const int4*)(hist + b * 1024))[t];
    red[t] = v.x + v.y + v.z + v.w;
    __syncthreads();
    for (int o = 128; o > 0; o >>= 1) {
        if (t < o) red[t] += red[t + o];
        __syncthreads();
    }
    if (t == 0) partials[b] = red[0];
}

__global__ void k_scanB(int* __restrict__ partials, int* __restrict__ offs_tail) {
    __shared__ int s1[256], s2[256];
    int t = threadIdx.x;
    int v[4]; int sum = 0;
    #pragma unroll
    for (int i = 0; i < 4; ++i) {
        int j = t * 4 + i;
        v[i] = (j < NBLK_SCAN) ? partials[j] : 0;
        sum += v[i];
    }
    s1[t] = sum; __syncthreads();
    int* cur = s1; int* nxt = s2;
    for (int o = 1; o < 256; o <<= 1) {
        nxt[t] = cur[t] + ((t >= o) ? cur[t - o] : 0);
        __syncthreads();
        int* tmp = cur; cur = nxt; nxt = tmp;
    }
    int run = cur[t] - sum;
    #pragma unroll
    for (int i = 0; i < 4; ++i) {
        int j = t * 4 + i;
        if (j < NBLK_SCAN) partials[j] = run;
        run += v[i];
    }
    if (t == 255) offs_tail[0] = cur[255];
}

__global__ void k_scanC(const int* __restrict__ hist, const int* __restrict__ partials,
                        int* __restrict__ offs, int* __restrict__ curp) {
    __shared__ int s1[256], s2[256];
    int b = blockIdx.x, t = threadIdx.x;
    int4 v = ((const int4*)(hist + b * 1024))[t];
    int sum = v.x + v.y + v.z + v.w;
    s1[t] = sum; __syncthreads();
    int* cur = s1; int* nxt = s2;
    for (int o = 1; o < 256; o <<= 1) {
        nxt[t] = cur[t] + ((t >= o) ? cur[t - o] : 0);
        __syncthreads();
        int* tmp = cur; cur = nxt; nxt = tmp;
    }
    int base = partials[b] + cur[t] - sum;
    int4 w;
    w.x = base;
    w.y = base + v.x;
    w.z = w.y + v.y;
    w.w = w.z + v.z;
    ((int4*)(offs + b * 1024))[t] = w;
    ((int4*)(curp + b * 1024))[t] = w;
}

__global__ void k_scatterK(const int* __restrict__ src, const int* __restrict__ dst,
                           const int* __restrict__ rel, int* __restrict__ cur,
                           unsigned int* __restrict__ srcs) {
    int e = blockIdx.x * blockDim.x + threadIdx.x;
    if (e < N_EDGES) {
        int pos = atomicAdd(&cur[dst[e]], 1);
        srcs[pos] = ((unsigned int)rel[e] << 16) | (unsigned int)src[e];
    }
}

// ---- Phase A: T[j][v][:] = X[v] @ W[r0+j], dense 128x128 tile GEMM ----
__global__ __launch_bounds__(256) void k_phaseA(
    const unsigned short* __restrict__ x, const unsigned short* __restrict__ Wb,
    unsigned short* __restrict__ T, int r0)
{
    __shared__ unsigned short Xs[128 * 136];             // 34816 B

    int tid = threadIdx.x;
    int t = blockIdx.x % NT_A;
    int j = blockIdx.x / NT_A;
    int rel = r0 + j;
    int v0 = t * 128;
    int w = tid >> 6, l = tid & 63;
    int nl = l & 15, q = l >> 4;

    {   // stage X tile: 2 threads/row, 64 elems each
        int row = tid >> 1, half = tid & 1;
        const uint4* xp = (const uint4*)(x + (v0 + row) * 128 + half * 64);
        uint4* lp = (uint4*)(&Xs[row * 136 + half * 64]);
        #pragma unroll
        for (int i = 0; i < 8; ++i) lp[i] = xp[i];
    }
    __syncthreads();

    bf16x8 Bf[2][4];
    const unsigned short* wr = Wb + rel * 16384;
    #pragma unroll
    for (int nt = 0; nt < 2; ++nt) {
        int n = w * 32 + nt * 16 + nl;
        #pragma unroll
        for (int kc = 0; kc < 4; ++kc)
            Bf[nt][kc] = *(const bf16x8*)(wr + n * 128 + kc * 32 + q * 8);
    }

    unsigned short* Tb = T + (size_t)j * (N_PAD * DIM) + (size_t)v0 * DIM;

    #pragma unroll
    for (int m = 0; m < 8; ++m) {
        f32x4 a0 = {0.f,0.f,0.f,0.f}, a1 = {0.f,0.f,0.f,0.f};
        #pragma unroll
        for (int kc = 0; kc < 4; ++kc) {
            bf16x8 a = *(const bf16x8*)(&Xs[(m * 16 + nl) * 136 + kc * 32 + q * 8]);
            a0 = __builtin_amdgcn_mfma_f32_16x16x32_bf16(a, Bf[0][kc], a0, 0, 0, 0);
            a1 = __builtin_amdgcn_mfma_f32_16x16x32_bf16(a, Bf[1][kc], a1, 0, 0, 0);
        }
        int col = w * 32 + nl;                           // C: col=lane&15, row=q*4+reg
        #pragma unroll
        for (int reg = 0; reg < 4; ++reg) {
            int node = m * 16 + q * 4 + reg;
            Tb[node * DIM + col]      = f2bf(a0[reg]);
            Tb[node * DIM + col + 16] = f2bf(a1[reg]);
        }
    }
}

// ---- Phase B: per dst, sum T rows of its edges (rels in [r0,r0+cntR)) ----
__global__ __launch_bounds__(256) void k_phaseB(
    const unsigned short* __restrict__ T, const unsigned int* __restrict__ srcs,
    const int* __restrict__ offs, unsigned short* __restrict__ agg,
    const float* __restrict__ bias, int r0, int cntR, int first,
    unsigned short* __restrict__ out_relu)
{
    __shared__ int sOffs[65];
    __shared__ float sBias[128];
    int tid = threadIdx.x;
    int v0 = blockIdx.x * 64;
    if (tid < 65) sOffs[tid] = offs[v0 + tid];
    if (tid < 32) ((float4*)sBias)[tid] = ((const float4*)bias)[tid];
    __syncthreads();

    int g = tid >> 2, s = tid & 3;
    int dst = v0 + g;
    float qa[32];
    #pragma unroll
    for (int i = 0; i < 32; ++i) qa[i] = 0.f;
    if (first) {
        #pragma unroll
        for (int i = 0; i < 32; ++i) qa[i] = sBias[s * 32 + i];
    } else {
        const uint4* ap = (const uint4*)(agg + dst * DIM + s * 32);
        uint4 u0 = ap[0], u1 = ap[1], u2 = ap[2], u3 = ap[3];
        accum8(qa, u0); accum8(qa + 8, u1); accum8(qa + 16, u2); accum8(qa + 24, u3);
    }

    int beg = sOffs[g], end = sOffs[g + 1];
    for (int e = beg; e < end; ++e) {
        unsigned int rec = srcs[e];
        unsigned int rr = (rec >> 16) - (unsigned int)r0;
        if (rr < (unsigned int)cntR) {
            const uint4* tp = (const uint4*)(T + ((size_t)rr * N_PAD + (rec & 0xffffu)) * DIM + s * 32);
            uint4 u0 = tp[0], u1 = tp[1], u2 = tp[2], u3 = tp[3];
            accum8(qa, u0); accum8(qa + 8, u1); accum8(qa + 16, u2); accum8(qa + 24, u3);
        }
    }
    if (r0 + cntR == 17) {                               // self-loop slot in this pass
        const uint4* tp = (const uint4*)(T + ((size_t)(16 - r0) * N_PAD + dst) * DIM + s * 32);
        uint4 u0 = tp[0], u1 = tp[1], u2 = tp[2], u3 = tp[3];
        accum8(qa, u0); accum8(qa + 8, u1); accum8(qa + 16, u2); accum8(qa + 24, u3);
    }

    if (out_relu) {                                      // final pass, layer-1: relu->x2
        float qr[32];
        #pragma unroll
        for (int i = 0; i < 32; ++i) qr[i] = fmaxf(qa[i], 0.f);
        pack32(qr, out_relu + dst * DIM + s * 32);
    } else {                                             // store partial / final agg (bf16)
        pack32(qa, agg + dst * DIM + s * 32);
    }
}

__global__ void k_pool(const unsigned short* __restrict__ agg2, const int* __restrict__ gids,
                       float* __restrict__ hg_sum, int* __restrict__ cnt)
{
    int d  = threadIdx.x;                    // 128
    int n0 = blockIdx.x * POOL_CH;
    int nend = min(n0 + POOL_CH, N_NODES);
    int curg = gids[n0];
    float run = 0.f;
    for (int n = n0; n < nend; ++n) {
        int g = gids[n];
        if (g != curg) { atomAddF(&hg_sum[curg*DIM + d], run); run = 0.f; curg = g; }
        run += fmaxf(bf2f((unsigned int)agg2[n*DIM + d]), 0.f);
    }
    atomAddF(&hg_sum[curg*DIM + d], run);
    if (d == 0) {
        int cg = gids[n0]; int rl = 0;
        for (int n = n0; n < nend; ++n) {
            int g = gids[n];
            if (g != cg) { atomicAdd(&cnt[cg], rl); rl = 0; cg = g; }
            rl++;
        }
        atomicAdd(&cnt[cg], rl);
    }
}

__global__ __launch_bounds__(256) void k_head(
    const float* __restrict__ hg_sum, const int* __restrict__ cnt,
    const float* __restrict__ Wfc, const float* __restrict__ bfc,
    const float* __restrict__ Wc, const float* __restrict__ bc,
    float* __restrict__ out)
{
    int g = blockIdx.x, t = threadIdx.x;
    __shared__ float hgl[DIM];
    __shared__ float fcl[FC_DIM];
    __shared__ float lg[N_CLASSES];
    if (t < DIM) {
        float c = (float)max(cnt[g], 1);
        hgl[t] = hg_sum[g*DIM + t] / c;
    }
    __syncthreads();
    {
        float sv = bfc[t];
        #pragma unroll 4
        for (int k = 0; k < DIM; ++k) sv += hgl[k] * Wfc[k*FC_DIM + t];
        fcl[t] = fmaxf(sv, 0.f);
    }
    __syncthreads();
    if (t < N_CLASSES) {
        float lgt = bc[t];
        #pragma unroll 4
        for (int k = 0; k < FC_DIM; ++k) lgt += fcl[k] * Wc[k*N_CLASSES + t];
        lg[t] = lgt;
    }
    __syncthreads();
    if (t < N_CLASSES) {
        float m = lg[0];
        #pragma unroll
        for (int c = 1; c < N_CLASSES; ++c) m = fmaxf(m, lg[c]);
        float sden = 0.f;
        #pragma unroll
        for (int c = 0; c < N_CLASSES; ++c) sden += expf(lg[c] - m);
        out[g*N_CLASSES + t] = expf(lg[t] - m) / sden;
    }
}

extern "C" void kernel_launch(void* const* d_in, const int* in_sizes, int n_in,
                              void* d_out, int out_size, void* d_ws, size_t ws_size,
                              hipStream_t stream)
{
    const float* h   = (const float*)d_in[0];
    const int*   src = (const int*)d_in[1];
    const int*   dst = (const int*)d_in[2];
    const int*   rel = (const int*)d_in[3];
    const int*   gid = (const int*)d_in[4];
    const float* W1  = (const float*)d_in[5];
    const float* Ws1 = (const float*)d_in[6];
    const float* b1  = (const float*)d_in[7];
    const float* W2  = (const float*)d_in[8];
    const float* Ws2 = (const float*)d_in[9];
    const float* b2  = (const float*)d_in[10];
    const float* Wfc = (const float*)d_in[11];
    const float* bfc = (const float*)d_in[12];
    const float* Wc  = (const float*)d_in[13];
    const float* bc  = (const float*)d_in[14];
    float* out = (float*)d_out;

    char* ws = (char*)d_ws;
    int*   hist  = (int*)(ws + WS_HIST);
    float* hgsum = (float*)(ws + WS_HG);
    int*   cnt   = (int*)(ws + WS_CNT);
    int*   offs  = (int*)(ws + WS_OFFS);
    int*   cur   = (int*)(ws + WS_CUR);
    int*   part  = (int*)(ws + WS_PART);
    unsigned int* srcs = (unsigned int*)(ws + WS_SRCS);
    unsigned short* x1  = (unsigned short*)(ws + WS_X1);
    unsigned short* x2  = (unsigned short*)(ws + WS_X2);
    unsigned short* agg = (unsigned short*)(ws + WS_AGG);
    unsigned short* Wb  = (unsigned short*)(ws + WS_WB);
    unsigned short* T   = (unsigned short*)(ws + WS_T);

    // how many rel-slots of T fit in ws (constant per harness -> capture-safe)
    int slots = 1;
    if (ws_size > (size_t)WS_T) {
        unsigned long long avail = (unsigned long long)ws_size - WS_T;
        slots = (int)(avail / SLOT_BYTES);
        if (slots > 17) slots = 17;
        if (slots < 1) slots = 1;
    }

    hipMemsetAsync(hist, 0, MEMSET_SZ, stream);

    k_convX<<<(N_PAD * DIM) / 256, 256, 0, stream>>>(h, x1);
    k_convW<<<(2 * 17 * 16384) / 256, 256, 0, stream>>>(W1, Ws1, W2, Ws2, Wb);

    k_histK<<<(N_EDGES + 255) / 256, 256, 0, stream>>>(dst, hist);
    k_scanA<<<NBLK_SCAN, 256, 0, stream>>>(hist, part);
    k_scanB<<<1, 256, 0, stream>>>(part, offs + NBINS_D);
    k_scanC<<<NBLK_SCAN, 256, 0, stream>>>(hist, part, offs, cur);
    k_scatterK<<<(N_EDGES + 255) / 256, 256, 0, stream>>>(src, dst, rel, cur, srcs);

    for (int layer = 0; layer < 2; ++layer) {
        const unsigned short* xin = layer ? x2 : x1;
        const unsigned short* WbL = Wb + layer * 17 * 16384;
        const float* bL = layer ? b2 : b1;
        for (int r0 = 0; r0 < 17; r0 += slots) {
            int c = 17 - r0; if (c > slots) c = slots;
            int lastP = (r0 + c == 17);
            k_phaseA<<<c * NT_A, 256, 0, stream>>>(xin, WbL, T, r0);
            k_phaseB<<<NBLK_B, 256, 0, stream>>>(T, srcs, offs, agg, bL, r0, c,
                                                 r0 == 0,
                                                 (layer == 0 && lastP) ? x2 : nullptr);
        }
    }

    k_pool<<<NBLK_B, 128, 0, stream>>>(agg, gid, hgsum, cnt);
    k_head<<<N_GRAPHS, 256, 0, stream>>>(hgsum, cnt, Wfc, bfc, Wc, bc, out);
}

// Round 7
// 506.781 us; speedup vs baseline: 1.5759x; 1.0180x over previous
//
#include <hip/hip_runtime.h>
#include <hip/hip_bf16.h>

#define N_NODES   50000
#define N_PAD     50048                 // ceil64 (= 391*128)
#define N_EDGES   800000
#define N_REL     16
#define N_GRAPHS  64
#define DIM       128
#define FC_DIM    256
#define N_CLASSES 16

#define NBINS_D   50176                 // dst bins padded to 49*1024
#define NBLK_SCAN 49
#define NBLK_B    782                   // N_PAD/64
#define POOL_CH   64
#define GRP_A     6

// ---- ws layout (bytes) ----
#define WS_HIST   0                     // 50176*4 = 200704 } contiguous
#define WS_HG     200704                // 32768            } memset
#define WS_CNT    233472                // 256              } region
#define MEMSET_SZ 233728
#define WS_OFFS   233728                // 50208*4 = 200832
#define WS_CUR    434560                // 200704
#define WS_PART   635264                // 256
#define WS_SRCS   635520                // 800000*4 = 3200000
#define WS_X1     3835520               // 50048*128*2 = 12812288
#define WS_X2     16647808              // 12812288
#define WS_AGG    29460096              // bf16 agg: 12812288
#define WS_WB     42272384              // 2*17*128*128*2 = 1114112
#define WS_T      43386496              // + slots * SLOT_BYTES
#define SLOT_BYTES 12812288ull          // N_PAD*128*2

typedef __attribute__((ext_vector_type(8))) short bf16x8;
typedef __attribute__((ext_vector_type(4))) float f32x4;

__device__ __forceinline__ void atomAddF(float* p, float v) {
#if defined(__gfx90a__) || defined(__gfx942__) || defined(__gfx950__)
    unsafeAtomicAdd(p, v);
#else
    atomicAdd(p, v);
#endif
}

__device__ __forceinline__ float bf2f(unsigned int u) {
    union { float f; unsigned int i; } x; x.i = u << 16; return x.f;
}
__device__ __forceinline__ unsigned short f2bf(float f) {
    union { float f; unsigned int u; } x; x.f = f;
    unsigned int r = x.u + 0x7fff + ((x.u >> 16) & 1);
    return (unsigned short)(r >> 16);
}
__device__ __forceinline__ void accum8(float* qa, uint4 u) {
    qa[0] += bf2f(u.x & 0xffff); qa[1] += bf2f(u.x >> 16);
    qa[2] += bf2f(u.y & 0xffff); qa[3] += bf2f(u.y >> 16);
    qa[4] += bf2f(u.z & 0xffff); qa[5] += bf2f(u.z >> 16);
    qa[6] += bf2f(u.w & 0xffff); qa[7] += bf2f(u.w >> 16);
}
__device__ __forceinline__ void pack16(const float* qa, unsigned short* dst) {
    #pragma unroll
    for (int j = 0; j < 2; ++j) {
        uint4 w;
        w.x = ((unsigned int)f2bf(qa[j*8+1]) << 16) | f2bf(qa[j*8+0]);
        w.y = ((unsigned int)f2bf(qa[j*8+3]) << 16) | f2bf(qa[j*8+2]);
        w.z = ((unsigned int)f2bf(qa[j*8+5]) << 16) | f2bf(qa[j*8+4]);
        w.w = ((unsigned int)f2bf(qa[j*8+7]) << 16) | f2bf(qa[j*8+6]);
        ((uint4*)dst)[j] = w;
    }
}

__global__ void k_convX(const float* __restrict__ h, unsigned short* __restrict__ x1) {
    int i = blockIdx.x * blockDim.x + threadIdx.x;      // over N_PAD*DIM
    int v = i >> 7;
    x1[i] = (v < N_NODES) ? f2bf(h[i]) : (unsigned short)0;
}

// Wb[l][r][n][k] = bf16(W_l[r][k][n]); r==16 -> Ws_l
__global__ void k_convW(const float* __restrict__ W1, const float* __restrict__ Ws1,
                        const float* __restrict__ W2, const float* __restrict__ Ws2,
                        unsigned short* __restrict__ Wb) {
    int id = blockIdx.x * blockDim.x + threadIdx.x;     // 2*17*16384
    int l = id / 278528, rem = id % 278528;
    int r = rem >> 14, rr = rem & 16383;
    int n = rr >> 7, k = rr & 127;
    const float* W  = l ? W2 : W1;
    const float* Ws = l ? Ws2 : Ws1;
    float v = (r < 16) ? W[r * 16384 + k * 128 + n] : Ws[k * 128 + n];
    Wb[id] = f2bf(v);
}

__global__ void k_histK(const int* __restrict__ dst, int* __restrict__ hist) {
    int e = blockIdx.x * blockDim.x + threadIdx.x;
    if (e < N_EDGES) atomicAdd(&hist[dst[e]], 1);
}

__global__ void k_scanA(const int* __restrict__ hist, int* __restrict__ partials) {
    __shared__ int red[256];
    int b = blockIdx.x, t = threadIdx.x;
    int4 v = ((const int4*)(hist + b * 1024))[t];
    red[t] = v.x + v.y + v.z + v.w;
    __syncthreads();
    for (int o = 128; o > 0; o >>= 1) {
        if (t < o) red[t] += red[t + o];
        __syncthreads();
    }
    if (t == 0) partials[b] = red[0];
}

__global__ void k_scanB(int* __restrict__ partials, int* __restrict__ offs_tail) {
    __shared__ int s1[256], s2[256];
    int t = threadIdx.x;
    int v[4]; int sum = 0;
    #pragma unroll
    for (int i = 0; i < 4; ++i) {
        int j = t * 4 + i;
        v[i] = (j < NBLK_SCAN) ? partials[j] : 0;
        sum += v[i];
    }
    s1[t] = sum; __syncthreads();
    int* cur = s1; int* nxt = s2;
    for (int o = 1; o < 256; o <<= 1) {
        nxt[t] = cur[t] + ((t >= o) ? cur[t - o] : 0);
        __syncthreads();
        int* tmp = cur; cur = nxt; nxt = tmp;
    }
    int run = cur[t] - sum;
    #pragma unroll
    for (int i = 0; i < 4; ++i) {
        int j = t * 4 + i;
        if (j < NBLK_SCAN) partials[j] = run;
        run += v[i];
    }
    if (t == 255) offs_tail[0] = cur[255];
}

__global__ void k_scanC(const int* __restrict__ hist, const int* __restrict__ partials,
                        int* __restrict__ offs, int* __restrict__ curp) {
    __shared__ int s1[256], s2[256];
    int b = blockIdx.x, t = threadIdx.x;
    int4 v = ((const int4*)(hist + b * 1024))[t];
    int sum = v.x + v.y + v.z + v.w;
    s1[t] = sum; __syncthreads();
    int* cur = s1; int* nxt = s2;
    for (int o = 1; o < 256; o <<= 1) {
        nxt[t] = cur[t] + ((t >= o) ? cur[t - o] : 0);
        __syncthreads();
        int* tmp = cur; cur = nxt; nxt = tmp;
    }
    int base = partials[b] + cur[t] - sum;
    int4 w;
    w.x = base;
    w.y = base + v.x;
    w.z = w.y + v.y;
    w.w = w.z + v.z;
    ((int4*)(offs + b * 1024))[t] = w;
    ((int4*)(curp + b * 1024))[t] = w;
}

__global__ void k_scatterK(const int* __restrict__ src, const int* __restrict__ dst,
                           const int* __restrict__ rel, int* __restrict__ cur,
                           unsigned int* __restrict__ srcs) {
    int e = blockIdx.x * blockDim.x + threadIdx.x;
    if (e < N_EDGES) {
        int pos = atomicAdd(&cur[dst[e]], 1);
        srcs[pos] = ((unsigned int)rel[e] << 16) | (unsigned int)src[e];
    }
}

// ---- Phase A v2: block stages 64-row X tile once, loops GRP_A rels ----
__global__ __launch_bounds__(256) void k_phaseA(
    const unsigned short* __restrict__ x, const unsigned short* __restrict__ Wb,
    unsigned short* __restrict__ T, int r0, int cnt)
{
    __shared__ unsigned short Xs[64 * 136];              // 17408 B

    int tid = threadIdx.x;
    int v0 = blockIdx.x * 64;
    int rbase = r0 + blockIdx.y * GRP_A;
    int w = tid >> 6, l = tid & 63;
    int nl = l & 15, q = l >> 4;

    {   // stage X tile: 4 threads/row, 4 uint4 each
        int row = tid >> 2, c0 = tid & 3;
        const uint4* xp = (const uint4*)(x + (v0 + row) * 128);
        uint4* lp = (uint4*)(&Xs[row * 136]);
        #pragma unroll
        for (int i = 0; i < 4; ++i) lp[c0 + 4 * i] = xp[c0 + 4 * i];
    }
    __syncthreads();

    int rend = rbase + GRP_A;
    if (rend > r0 + cnt) rend = r0 + cnt;
    for (int rel = rbase; rel < rend; ++rel) {
        bf16x8 Bf[2][4];
        const unsigned short* wr = Wb + rel * 16384;
        #pragma unroll
        for (int nt = 0; nt < 2; ++nt) {
            int n = w * 32 + nt * 16 + nl;
            #pragma unroll
            for (int kc = 0; kc < 4; ++kc)
                Bf[nt][kc] = *(const bf16x8*)(wr + n * 128 + kc * 32 + q * 8);
        }
        unsigned short* Tb = T + (size_t)(rel - r0) * (N_PAD * DIM) + (size_t)v0 * DIM;
        #pragma unroll
        for (int m = 0; m < 4; ++m) {
            f32x4 a0 = {0.f,0.f,0.f,0.f}, a1 = {0.f,0.f,0.f,0.f};
            #pragma unroll
            for (int kc = 0; kc < 4; ++kc) {
                bf16x8 a = *(const bf16x8*)(&Xs[(m * 16 + nl) * 136 + kc * 32 + q * 8]);
                a0 = __builtin_amdgcn_mfma_f32_16x16x32_bf16(a, Bf[0][kc], a0, 0, 0, 0);
                a1 = __builtin_amdgcn_mfma_f32_16x16x32_bf16(a, Bf[1][kc], a1, 0, 0, 0);
            }
            int col = w * 32 + nl;                       // C: col=lane&15, row=q*4+reg
            #pragma unroll
            for (int reg = 0; reg < 4; ++reg) {
                int node = m * 16 + q * 4 + reg;
                Tb[node * DIM + col]      = f2bf(a0[reg]);
                Tb[node * DIM + col + 16] = f2bf(a1[reg]);
            }
        }
    }
}

// ---- Phase B v2: 32 dsts/block, 8 lanes/dst ----
__global__ __launch_bounds__(256) void k_phaseB(
    const unsigned short* __restrict__ T, const unsigned int* __restrict__ srcs,
    const int* __restrict__ offs, unsigned short* __restrict__ agg,
    const float* __restrict__ bias, int r0, int cntR, int first,
    unsigned short* __restrict__ out_relu)
{
    __shared__ int sOffs[33];
    __shared__ float sBias[128];
    int tid = threadIdx.x;
    int v0 = blockIdx.x * 32;
    if (tid < 33) sOffs[tid] = offs[v0 + tid];
    if (tid >= 64 && tid < 96) ((float4*)sBias)[tid - 64] = ((const float4*)bias)[tid - 64];
    __syncthreads();

    int g = tid >> 3, s = tid & 7;
    int dst = v0 + g;
    float qa[16];
    #pragma unroll
    for (int i = 0; i < 16; ++i) qa[i] = 0.f;
    if (first) {
        #pragma unroll
        for (int i = 0; i < 16; ++i) qa[i] = sBias[s * 16 + i];
    } else {
        const uint4* ap = (const uint4*)(agg + dst * DIM + s * 16);
        uint4 u0 = ap[0], u1 = ap[1];
        accum8(qa, u0); accum8(qa + 8, u1);
    }

    int beg = sOffs[g], end = sOffs[g + 1];
    for (int e = beg; e < end; ++e) {
        unsigned int rec = srcs[e];
        unsigned int rr = (rec >> 16) - (unsigned int)r0;
        if (rr < (unsigned int)cntR) {
            const uint4* tp = (const uint4*)(T + ((size_t)rr * N_PAD + (rec & 0xffffu)) * DIM + s * 16);
            uint4 u0 = tp[0], u1 = tp[1];
            accum8(qa, u0); accum8(qa + 8, u1);
        }
    }
    if (r0 + cntR == 17) {                               // self-loop slot in this pass
        const uint4* tp = (const uint4*)(T + ((size_t)(16 - r0) * N_PAD + dst) * DIM + s * 16);
        uint4 u0 = tp[0], u1 = tp[1];
        accum8(qa, u0); accum8(qa + 8, u1);
    }

    if (out_relu) {                                      // final pass, layer-1: relu->x2
        float qr[16];
        #pragma unroll
        for (int i = 0; i < 16; ++i) qr[i] = fmaxf(qa[i], 0.f);
        pack16(qr, out_relu + dst * DIM + s * 16);
    } else {
        pack16(qa, agg + dst * DIM + s * 16);
    }
}

__global__ void k_pool(const unsigned short* __restrict__ agg2, const int* __restrict__ gids,
                       float* __restrict__ hg_sum, int* __restrict__ cnt)
{
    int d  = threadIdx.x;                    // 128
    int n0 = blockIdx.x * POOL_CH;
    int nend = min(n0 + POOL_CH, N_NODES);
    int curg = gids[n0];
    float run = 0.f;
    for (int n = n0; n < nend; ++n) {
        int g = gids[n];
        if (g != curg) { atomAddF(&hg_sum[curg*DIM + d], run); run = 0.f; curg = g; }
        run += fmaxf(bf2f((unsigned int)agg2[n*DIM + d]), 0.f);
    }
    atomAddF(&hg_sum[curg*DIM + d], run);
    if (d == 0) {
        int cg = gids[n0]; int rl = 0;
        for (int n = n0; n < nend; ++n) {
            int g = gids[n];
            if (g != cg) { atomicAdd(&cnt[cg], rl); rl = 0; cg = g; }
            rl++;
        }
        atomicAdd(&cnt[cg], rl);
    }
}

__global__ __launch_bounds__(256) void k_head(
    const float* __restrict__ hg_sum, const int* __restrict__ cnt,
    const float* __restrict__ Wfc, const float* __restrict__ bfc,
    const float* __restrict__ Wc, const float* __restrict__ bc,
    float* __restrict__ out)
{
    int g = blockIdx.x, t = threadIdx.x;
    __shared__ float hgl[DIM];
    __shared__ float fcl[FC_DIM];
    __shared__ float lg[N_CLASSES];
    if (t < DIM) {
        float c = (float)max(cnt[g], 1);
        hgl[t] = hg_sum[g*DIM + t] / c;
    }
    __syncthreads();
    {
        float sv = bfc[t];
        #pragma unroll 4
        for (int k = 0; k < DIM; ++k) sv += hgl[k] * Wfc[k*FC_DIM + t];
        fcl[t] = fmaxf(sv, 0.f);
    }
    __syncthreads();
    if (t < N_CLASSES) {
        float lgt = bc[t];
        #pragma unroll 4
        for (int k = 0; k < FC_DIM; ++k) lgt += fcl[k] * Wc[k*N_CLASSES + t];
        lg[t] = lgt;
    }
    __syncthreads();
    if (t < N_CLASSES) {
        float m = lg[0];
        #pragma unroll
        for (int c = 1; c < N_CLASSES; ++c) m = fmaxf(m, lg[c]);
        float sden = 0.f;
        #pragma unroll
        for (int c = 0; c < N_CLASSES; ++c) sden += expf(lg[c] - m);
        out[g*N_CLASSES + t] = expf(lg[t] - m) / sden;
    }
}

extern "C" void kernel_launch(void* const* d_in, const int* in_sizes, int n_in,
                              void* d_out, int out_size, void* d_ws, size_t ws_size,
                              hipStream_t stream)
{
    const float* h   = (const float*)d_in[0];
    const int*   src = (const int*)d_in[1];
    const int*   dst = (const int*)d_in[2];
    const int*   rel = (const int*)d_in[3];
    const int*   gid = (const int*)d_in[4];
    const float* W1  = (const float*)d_in[5];
    const float* Ws1 = (const float*)d_in[6];
    const float* b1  = (const float*)d_in[7];
    const float* W2  = (const float*)d_in[8];
    const float* Ws2 = (const float*)d_in[9];
    const float* b2  = (const float*)d_in[10];
    const float* Wfc = (const float*)d_in[11];
    const float* bfc = (const float*)d_in[12];
    const float* Wc  = (const float*)d_in[13];
    const float* bc  = (const float*)d_in[14];
    float* out = (float*)d_out;

    char* ws = (char*)d_ws;
    int*   hist  = (int*)(ws + WS_HIST);
    float* hgsum = (float*)(ws + WS_HG);
    int*   cnt   = (int*)(ws + WS_CNT);
    int*   offs  = (int*)(ws + WS_OFFS);
    int*   cur   = (int*)(ws + WS_CUR);
    int*   part  = (int*)(ws + WS_PART);
    unsigned int* srcs = (unsigned int*)(ws + WS_SRCS);
    unsigned short* x1  = (unsigned short*)(ws + WS_X1);
    unsigned short* x2  = (unsigned short*)(ws + WS_X2);
    unsigned short* agg = (unsigned short*)(ws + WS_AGG);
    unsigned short* Wb  = (unsigned short*)(ws + WS_WB);
    unsigned short* T   = (unsigned short*)(ws + WS_T);

    // how many rel-slots of T fit in ws (constant per harness -> capture-safe)
    int slots = 1;
    if (ws_size > (size_t)WS_T) {
        unsigned long long avail = (unsigned long long)ws_size - WS_T;
        slots = (int)(avail / SLOT_BYTES);
        if (slots > 17) slots = 17;
        if (slots < 1) slots = 1;
    }

    hipMemsetAsync(hist, 0, MEMSET_SZ, stream);

    k_convX<<<(N_PAD * DIM) / 256, 256, 0, stream>>>(h, x1);
    k_convW<<<(2 * 17 * 16384) / 256, 256, 0, stream>>>(W1, Ws1, W2, Ws2, Wb);

    k_histK<<<(N_EDGES + 255) / 256, 256, 0, stream>>>(dst, hist);
    k_scanA<<<NBLK_SCAN, 256, 0, stream>>>(hist, part);
    k_scanB<<<1, 256, 0, stream>>>(part, offs + NBINS_D);
    k_scanC<<<NBLK_SCAN, 256, 0, stream>>>(hist, part, offs, cur);
    k_scatterK<<<(N_EDGES + 255) / 256, 256, 0, stream>>>(src, dst, rel, cur, srcs);

    for (int layer = 0; layer < 2; ++layer) {
        const unsigned short* xin = layer ? x2 : x1;
        const unsigned short* WbL = Wb + layer * 17 * 16384;
        const float* bL = layer ? b2 : b1;
        for (int r0 = 0; r0 < 17; r0 += slots) {
            int c = 17 - r0; if (c > slots) c = slots;
            int lastP = (r0 + c == 17);
            dim3 gA(NBLK_B, (c + GRP_A - 1) / GRP_A);
            k_phaseA<<<gA, 256, 0, stream>>>(xin, WbL, T, r0, c);
            k_phaseB<<<N_PAD / 32, 256, 0, stream>>>(T, srcs, offs, agg, bL, r0, c,
                                                     r0 == 0,
                                                     (layer == 0 && lastP) ? x2 : nullptr);
        }
    }

    k_pool<<<NBLK_B, 128, 0, stream>>>(agg, gid, hgsum, cnt);
    k_head<<<N_GRAPHS, 256, 0, stream>>>(hgsum, cnt, Wfc, bfc, Wc, bc, out);
}